// Round 1
// baseline (288.635 us; speedup 1.0000x reference)
//
#include <hip/hip_runtime.h>
#include <cstdint>
#include <cstddef>

#define HD 64
#define NH 16
#define BATCH 2
#define SEQ 2048
#define DIM 1024
#define SCALE 0.03125f   // 1024^-0.5
#define LOG2E 1.4426950408889634f

typedef short bf16x8 __attribute__((ext_vector_type(8)));
typedef float f32x4 __attribute__((ext_vector_type(4)));

static __device__ __forceinline__ unsigned short f2bf(float f) {
  union { float f; unsigned u; } a; a.f = f;
  unsigned r = a.u + 0x7fffu + ((a.u >> 16) & 1u);  // RNE
  return (unsigned short)(r >> 16);
}

static __device__ __forceinline__ f32x4 zero4() {
  f32x4 z; z[0] = 0.f; z[1] = 0.f; z[2] = 0.f; z[3] = 0.f; return z;
}

// ---------------- fp32 -> bf16 convert (vectorized) ----------------
__global__ void convert_x(const float* __restrict__ in, unsigned short* __restrict__ out, int n4) {
  int i = blockIdx.x * blockDim.x + threadIdx.x;
  if (i < n4) {
    float4 v = reinterpret_cast<const float4*>(in)[i];
    ushort4 o;
    o.x = f2bf(v.x); o.y = f2bf(v.y); o.z = f2bf(v.z); o.w = f2bf(v.w);
    reinterpret_cast<ushort4*>(out)[i] = o;
  }
}

// ---------------- transpose + convert: in[R][C] fp32 -> out[C][R] bf16 ----------------
__global__ void transpose_convert(const float* __restrict__ in, unsigned short* __restrict__ out,
                                  int R, int C) {
  __shared__ float tile[32][33];
  int bx = blockIdx.x * 32;  // col base of 'in'
  int by = blockIdx.y * 32;  // row base of 'in'
  int tx = threadIdx.x, ty = threadIdx.y;  // block (32,8)
  #pragma unroll
  for (int i = 0; i < 32; i += 8)
    tile[ty + i][tx] = in[(size_t)(by + ty + i) * C + bx + tx];
  __syncthreads();
  #pragma unroll
  for (int i = 0; i < 32; i += 8)
    out[(size_t)(bx + ty + i) * R + by + tx] = f2bf(tile[tx][ty + i]);
}

// ---------------- GEMM: C[m][n] = sum_k A[m][k] * Bt[n][k]  (A,Bt bf16; fp32 acc) -------
// mode 0: scatter epilogue into q/k/v [B,H,N,hd] bf16 (+bias)
// mode 1: fp32 epilogue into outf [M][DIM] (+bias)
__global__ __launch_bounds__(256) void gemm_bt(
    const unsigned short* __restrict__ A, const unsigned short* __restrict__ Bt,
    const float* __restrict__ bias, int K, int mode,
    unsigned short* __restrict__ qo, unsigned short* __restrict__ ko,
    unsigned short* __restrict__ vo, float* __restrict__ outf) {
  __shared__ __attribute__((aligned(16))) unsigned short As[64][72];
  __shared__ __attribute__((aligned(16))) unsigned short Bs[64][72];
  int tid = threadIdx.x;
  int lane = tid & 63;
  int w = tid >> 6;
  int wm = w >> 1, wn = w & 1;
  int m0 = blockIdx.y * 64, n0 = blockIdx.x * 64;
  int r0 = tid >> 3, c0 = (tid & 7) * 8;

  f32x4 acc[2][2];
  #pragma unroll
  for (int mr = 0; mr < 2; ++mr)
    #pragma unroll
    for (int nr = 0; nr < 2; ++nr) acc[mr][nr] = zero4();

  int nkt = K / 64;
  for (int kt = 0; kt < nkt; ++kt) {
    int k0 = kt * 64;
    uint4 a0 = *reinterpret_cast<const uint4*>(&A[(size_t)(m0 + r0) * K + k0 + c0]);
    uint4 a1 = *reinterpret_cast<const uint4*>(&A[(size_t)(m0 + r0 + 32) * K + k0 + c0]);
    uint4 b0 = *reinterpret_cast<const uint4*>(&Bt[(size_t)(n0 + r0) * K + k0 + c0]);
    uint4 b1 = *reinterpret_cast<const uint4*>(&Bt[(size_t)(n0 + r0 + 32) * K + k0 + c0]);
    *reinterpret_cast<uint4*>(&As[r0][c0]) = a0;
    *reinterpret_cast<uint4*>(&As[r0 + 32][c0]) = a1;
    *reinterpret_cast<uint4*>(&Bs[r0][c0]) = b0;
    *reinterpret_cast<uint4*>(&Bs[r0 + 32][c0]) = b1;
    __syncthreads();
    #pragma unroll
    for (int kc = 0; kc < 2; ++kc) {
      bf16x8 af[2], bfr[2];
      #pragma unroll
      for (int mr = 0; mr < 2; ++mr)
        af[mr] = *reinterpret_cast<const bf16x8*>(
            &As[wm * 32 + mr * 16 + (lane & 15)][kc * 32 + (lane >> 4) * 8]);
      #pragma unroll
      for (int nr = 0; nr < 2; ++nr)
        bfr[nr] = *reinterpret_cast<const bf16x8*>(
            &Bs[wn * 32 + nr * 16 + (lane & 15)][kc * 32 + (lane >> 4) * 8]);
      #pragma unroll
      for (int mr = 0; mr < 2; ++mr)
        #pragma unroll
        for (int nr = 0; nr < 2; ++nr)
          acc[mr][nr] = __builtin_amdgcn_mfma_f32_16x16x32_bf16(af[mr], bfr[nr], acc[mr][nr], 0, 0, 0);
    }
    __syncthreads();
  }

  #pragma unroll
  for (int mr = 0; mr < 2; ++mr)
    #pragma unroll
    for (int nr = 0; nr < 2; ++nr)
      #pragma unroll
      for (int j = 0; j < 4; ++j) {
        int grow = m0 + wm * 32 + mr * 16 + (lane >> 4) * 4 + j;
        int gcol = n0 + wn * 32 + nr * 16 + (lane & 15);
        float val = acc[mr][nr][j] + bias[gcol];
        if (mode == 0) {
          int which = gcol >> 10;         // 0=q 1=k 2=v
          int hh = (gcol >> 6) & 15;
          int d = gcol & 63;
          int bb = grow >> 11;
          int n = grow & 2047;
          unsigned short* dst = (which == 0) ? qo : ((which == 1) ? ko : vo);
          dst[((size_t)(bb * NH + hh) * SEQ + n) * HD + d] = f2bf(val);
        } else {
          outf[(size_t)grow * DIM + gcol] = val;
        }
      }
}

// ---------------- flash attention with zoom bias ----------------
// grid: (N/64) * B*H blocks; block 256 threads (4 waves, 16 q-rows each)
__global__ __launch_bounds__(256) void attn_kernel(
    const unsigned short* __restrict__ qb, const unsigned short* __restrict__ kb,
    const unsigned short* __restrict__ vb, const float* __restrict__ gamma,
    const float* __restrict__ dist, unsigned short* __restrict__ ab) {
  __shared__ __attribute__((aligned(16))) unsigned short Ks[64][72];
  __shared__ __attribute__((aligned(16))) unsigned short Vt[64][72];
  __shared__ __attribute__((aligned(16))) unsigned short Ps[4][16][72];
  int tid = threadIdx.x;
  int lane = tid & 63;
  int w = tid >> 6;
  int idx = blockIdx.x;
  int bh = idx & 31;         // consecutive blocks share q-tile -> dist L2/L3 reuse
  int qt = idx >> 5;
  int b = bh >> 4, h = bh & 15;
  int n0 = qt * 64;
  float gma = gamma[bh];

  const size_t base = (size_t)bh * SEQ * HD;

  // Q fragments hoisted to registers (A-operand layout: row=lane&15, k=8*(lane>>4)+j)
  const unsigned short* qrow =
      qb + base + (size_t)(n0 + w * 16 + (lane & 15)) * HD + (lane >> 4) * 8;
  bf16x8 qf[2];
  qf[0] = *reinterpret_cast<const bf16x8*>(qrow);
  qf[1] = *reinterpret_cast<const bf16x8*>(qrow + 32);

  f32x4 o[4];
  #pragma unroll
  for (int db = 0; db < 4; ++db) o[db] = zero4();
  float m_run[4] = {-INFINITY, -INFINITY, -INFINITY, -INFINITY};
  float l_run[4] = {0.f, 0.f, 0.f, 0.f};

  int r0 = tid >> 3, c0 = (tid & 7) * 8;
  int qrow0 = n0 + w * 16;

  for (int mt = 0; mt < SEQ / 64; ++mt) {
    int m0 = mt * 64;
    // stage K [64][64] row-major (padded)
    *reinterpret_cast<uint4*>(&Ks[r0][c0]) =
        *reinterpret_cast<const uint4*>(&kb[base + (size_t)(m0 + r0) * HD + c0]);
    *reinterpret_cast<uint4*>(&Ks[r0 + 32][c0]) =
        *reinterpret_cast<const uint4*>(&kb[base + (size_t)(m0 + r0 + 32) * HD + c0]);
    // stage V transposed: Vt[d][m]
    {
      uint4 v0 = *reinterpret_cast<const uint4*>(&vb[base + (size_t)(m0 + r0) * HD + c0]);
      uint4 v1 = *reinterpret_cast<const uint4*>(&vb[base + (size_t)(m0 + r0 + 32) * HD + c0]);
      unsigned e0[8] = {v0.x & 0xffffu, v0.x >> 16, v0.y & 0xffffu, v0.y >> 16,
                        v0.z & 0xffffu, v0.z >> 16, v0.w & 0xffffu, v0.w >> 16};
      unsigned e1[8] = {v1.x & 0xffffu, v1.x >> 16, v1.y & 0xffffu, v1.y >> 16,
                        v1.z & 0xffffu, v1.z >> 16, v1.w & 0xffffu, v1.w >> 16};
      #pragma unroll
      for (int i = 0; i < 8; ++i) {
        Vt[c0 + i][r0] = (unsigned short)e0[i];
        Vt[c0 + i][r0 + 32] = (unsigned short)e1[i];
      }
    }
    __syncthreads();

    // S = Q K^T : per wave 16x64, as 4 16x16 blocks
    f32x4 s[4];
    #pragma unroll
    for (int nb = 0; nb < 4; ++nb) {
      s[nb] = zero4();
      #pragma unroll
      for (int kc = 0; kc < 2; ++kc) {
        bf16x8 kf = *reinterpret_cast<const bf16x8*>(
            &Ks[nb * 16 + (lane & 15)][kc * 32 + (lane >> 4) * 8]);
        s[nb] = __builtin_amdgcn_mfma_f32_16x16x32_bf16(qf[kc], kf, s[nb], 0, 0, 0);
      }
    }
    // scale + zoom bias  (C layout: row=(lane>>4)*4+j, col=lane&15)
    float sv[4][4];
    #pragma unroll
    for (int nb = 0; nb < 4; ++nb)
      #pragma unroll
      for (int j = 0; j < 4; ++j) {
        int qr = qrow0 + (lane >> 4) * 4 + j;
        int mc = m0 + nb * 16 + (lane & 15);
        sv[nb][j] = s[nb][j] * SCALE - gma * dist[(size_t)qr * SEQ + mc];
      }
    // online softmax: row max over 64 cols (16-lane group reduce)
    float rm[4];
    #pragma unroll
    for (int j = 0; j < 4; ++j)
      rm[j] = fmaxf(fmaxf(sv[0][j], sv[1][j]), fmaxf(sv[2][j], sv[3][j]));
    #pragma unroll
    for (int off = 1; off < 16; off <<= 1)
      #pragma unroll
      for (int j = 0; j < 4; ++j)
        rm[j] = fmaxf(rm[j], __shfl_xor(rm[j], off, 64));

    float mn[4], corr[4];
    #pragma unroll
    for (int j = 0; j < 4; ++j) {
      mn[j] = fmaxf(m_run[j], rm[j]);
      corr[j] = exp2f((m_run[j] - mn[j]) * LOG2E);
      m_run[j] = mn[j];
    }
    float ps[4] = {0.f, 0.f, 0.f, 0.f};
    #pragma unroll
    for (int nb = 0; nb < 4; ++nb)
      #pragma unroll
      for (int j = 0; j < 4; ++j) {
        float p = exp2f((sv[nb][j] - mn[j]) * LOG2E);
        ps[j] += p;
        Ps[w][(lane >> 4) * 4 + j][nb * 16 + (lane & 15)] = f2bf(p);
      }
    #pragma unroll
    for (int off = 1; off < 16; off <<= 1)
      #pragma unroll
      for (int j = 0; j < 4; ++j)
        ps[j] += __shfl_xor(ps[j], off, 64);
    #pragma unroll
    for (int j = 0; j < 4; ++j)
      l_run[j] = l_run[j] * corr[j] + ps[j];
    #pragma unroll
    for (int db = 0; db < 4; ++db)
      #pragma unroll
      for (int j = 0; j < 4; ++j)
        o[db][j] *= corr[j];

    // O += P V   (A = P via per-wave LDS round-trip; B = V via transposed tile)
    #pragma unroll
    for (int kc = 0; kc < 2; ++kc) {
      bf16x8 pf = *reinterpret_cast<const bf16x8*>(
          &Ps[w][lane & 15][kc * 32 + (lane >> 4) * 8]);
      #pragma unroll
      for (int db = 0; db < 4; ++db) {
        bf16x8 vf = *reinterpret_cast<const bf16x8*>(
            &Vt[db * 16 + (lane & 15)][kc * 32 + (lane >> 4) * 8]);
        o[db] = __builtin_amdgcn_mfma_f32_16x16x32_bf16(pf, vf, o[db], 0, 0, 0);
      }
    }
    __syncthreads();
  }

  // epilogue: O /= l, write attn_out [B,N,H*hd] bf16
  #pragma unroll
  for (int db = 0; db < 4; ++db)
    #pragma unroll
    for (int j = 0; j < 4; ++j) {
      float ov = o[db][j] / l_run[j];
      size_t row = (size_t)b * SEQ + n0 + w * 16 + (lane >> 4) * 4 + j;
      ab[row * DIM + h * HD + db * 16 + (lane & 15)] = f2bf(ov);
    }
}

extern "C" void kernel_launch(void* const* d_in, const int* in_sizes, int n_in,
                              void* d_out, int out_size, void* d_ws, size_t ws_size,
                              hipStream_t stream) {
  const float* x     = (const float*)d_in[0];
  const float* gamma = (const float*)d_in[1];
  const float* dist  = (const float*)d_in[2];
  const float* Wqkv  = (const float*)d_in[3];
  const float* bqkv  = (const float*)d_in[4];
  const float* Wproj = (const float*)d_in[5];
  const float* bproj = (const float*)d_in[6];
  float* out = (float*)d_out;

  char* ws = (char*)d_ws;
  unsigned short* xb     = (unsigned short*)(ws);                 // 8,388,608 B
  unsigned short* wqkvt  = (unsigned short*)(ws + 8388608);       // 6,291,456 B
  unsigned short* wprojt = (unsigned short*)(ws + 14680064);      // 2,097,152 B
  unsigned short* qbuf   = (unsigned short*)(ws + 16777216);      // 8,388,608 B
  unsigned short* kbuf   = (unsigned short*)(ws + 25165824);      // 8,388,608 B
  unsigned short* vbuf   = (unsigned short*)(ws + 33554432);      // 8,388,608 B
  unsigned short* abuf   = (unsigned short*)(ws + 41943040);      // 8,388,608 B  (total 48 MiB)

  convert_x<<<4096, 256, 0, stream>>>(x, xb, (BATCH * SEQ * DIM) / 4);
  transpose_convert<<<dim3(96, 32), dim3(32, 8), 0, stream>>>(Wqkv, wqkvt, DIM, 3 * DIM);
  transpose_convert<<<dim3(32, 32), dim3(32, 8), 0, stream>>>(Wproj, wprojt, DIM, DIM);
  // QKV: [4096,1024] x [1024,3072]
  gemm_bt<<<dim3(48, 64), 256, 0, stream>>>(xb, wqkvt, bqkv, DIM, 0, qbuf, kbuf, vbuf, nullptr);
  // attention
  attn_kernel<<<(SEQ / 64) * BATCH * NH, 256, 0, stream>>>(qbuf, kbuf, vbuf, gamma, dist, abuf);
  // proj: [4096,1024] x [1024,1024]
  gemm_bt<<<dim3(16, 64), 256, 0, stream>>>(abuf, wprojt, bproj, DIM, 1, nullptr, nullptr, nullptr, out);
}

// Round 2
// 220.453 us; speedup vs baseline: 1.3093x; 1.3093x over previous
//
#include <hip/hip_runtime.h>
#include <cstdint>
#include <cstddef>

#define HD 64
#define NH 16
#define BATCH 2
#define SEQ 2048
#define DIM 1024
#define SCALE 0.03125f   // 1024^-0.5
#define LOG2E 1.4426950408889634f
#define QSCALE (SCALE * LOG2E)   // folded into q at QKV epilogue
#define PST 72                    // padded LDS stride (shorts)

typedef short bf16x8 __attribute__((ext_vector_type(8)));
typedef float f32x4 __attribute__((ext_vector_type(4)));

static __device__ __forceinline__ unsigned short f2bf(float f) {
  union { float f; unsigned u; } a; a.f = f;
  unsigned r = a.u + 0x7fffu + ((a.u >> 16) & 1u);  // RNE
  return (unsigned short)(r >> 16);
}

static __device__ __forceinline__ f32x4 zero4() {
  f32x4 z; z[0] = 0.f; z[1] = 0.f; z[2] = 0.f; z[3] = 0.f; return z;
}

// ---------------- fp32 -> bf16 convert (vectorized) ----------------
__global__ void convert_x(const float* __restrict__ in, unsigned short* __restrict__ out, int n4) {
  int i = blockIdx.x * blockDim.x + threadIdx.x;
  if (i < n4) {
    float4 v = reinterpret_cast<const float4*>(in)[i];
    ushort4 o;
    o.x = f2bf(v.x); o.y = f2bf(v.y); o.z = f2bf(v.z); o.w = f2bf(v.w);
    reinterpret_cast<ushort4*>(out)[i] = o;
  }
}

// ---------------- transpose + convert: in[R][C] fp32 -> out[C][R] bf16 ----------------
__global__ void transpose_convert(const float* __restrict__ in, unsigned short* __restrict__ out,
                                  int R, int C) {
  __shared__ float tile[32][33];
  int bx = blockIdx.x * 32;
  int by = blockIdx.y * 32;
  int tx = threadIdx.x, ty = threadIdx.y;  // block (32,8)
  #pragma unroll
  for (int i = 0; i < 32; i += 8)
    tile[ty + i][tx] = in[(size_t)(by + ty + i) * C + bx + tx];
  __syncthreads();
  #pragma unroll
  for (int i = 0; i < 32; i += 8)
    out[(size_t)(bx + ty + i) * R + by + tx] = f2bf(tile[tx][ty + i]);
}

// ---------------- GEMM: C[m][n] = sum_k A[m][k] * Bt[n][k]  (A,Bt bf16; fp32 acc) -------
// mode 0: scatter epilogue into q (pre-scaled)/k [B,H,N,hd] and v TRANSPOSED [B,H,hd,N]
// mode 1: fp32 epilogue into outf [M][DIM] (+bias)
__global__ __launch_bounds__(256) void gemm_bt(
    const unsigned short* __restrict__ A, const unsigned short* __restrict__ Bt,
    const float* __restrict__ bias, int K, int mode,
    unsigned short* __restrict__ qo, unsigned short* __restrict__ ko,
    unsigned short* __restrict__ vo, float* __restrict__ outf) {
  __shared__ __attribute__((aligned(16))) unsigned short As[64][72];
  __shared__ __attribute__((aligned(16))) unsigned short Bs[64][72];
  int tid = threadIdx.x;
  int lane = tid & 63;
  int w = tid >> 6;
  int wm = w >> 1, wn = w & 1;
  int m0 = blockIdx.y * 64, n0 = blockIdx.x * 64;
  int r0 = tid >> 3, c0 = (tid & 7) * 8;

  f32x4 acc[2][2];
  #pragma unroll
  for (int mr = 0; mr < 2; ++mr)
    #pragma unroll
    for (int nr = 0; nr < 2; ++nr) acc[mr][nr] = zero4();

  int nkt = K / 64;
  for (int kt = 0; kt < nkt; ++kt) {
    int k0 = kt * 64;
    uint4 a0 = *reinterpret_cast<const uint4*>(&A[(size_t)(m0 + r0) * K + k0 + c0]);
    uint4 a1 = *reinterpret_cast<const uint4*>(&A[(size_t)(m0 + r0 + 32) * K + k0 + c0]);
    uint4 b0 = *reinterpret_cast<const uint4*>(&Bt[(size_t)(n0 + r0) * K + k0 + c0]);
    uint4 b1 = *reinterpret_cast<const uint4*>(&Bt[(size_t)(n0 + r0 + 32) * K + k0 + c0]);
    *reinterpret_cast<uint4*>(&As[r0][c0]) = a0;
    *reinterpret_cast<uint4*>(&As[r0 + 32][c0]) = a1;
    *reinterpret_cast<uint4*>(&Bs[r0][c0]) = b0;
    *reinterpret_cast<uint4*>(&Bs[r0 + 32][c0]) = b1;
    __syncthreads();
    #pragma unroll
    for (int kc = 0; kc < 2; ++kc) {
      bf16x8 af[2], bfr[2];
      #pragma unroll
      for (int mr = 0; mr < 2; ++mr)
        af[mr] = *reinterpret_cast<const bf16x8*>(
            &As[wm * 32 + mr * 16 + (lane & 15)][kc * 32 + (lane >> 4) * 8]);
      #pragma unroll
      for (int nr = 0; nr < 2; ++nr)
        bfr[nr] = *reinterpret_cast<const bf16x8*>(
            &Bs[wn * 32 + nr * 16 + (lane & 15)][kc * 32 + (lane >> 4) * 8]);
      #pragma unroll
      for (int mr = 0; mr < 2; ++mr)
        #pragma unroll
        for (int nr = 0; nr < 2; ++nr)
          acc[mr][nr] = __builtin_amdgcn_mfma_f32_16x16x32_bf16(af[mr], bfr[nr], acc[mr][nr], 0, 0, 0);
    }
    __syncthreads();
  }

  #pragma unroll
  for (int mr = 0; mr < 2; ++mr)
    #pragma unroll
    for (int nr = 0; nr < 2; ++nr)
      #pragma unroll
      for (int j = 0; j < 4; ++j) {
        int grow = m0 + wm * 32 + mr * 16 + (lane >> 4) * 4 + j;
        int gcol = n0 + wn * 32 + nr * 16 + (lane & 15);
        float val = acc[mr][nr][j] + bias[gcol];
        if (mode == 0) {
          int which = gcol >> 10;         // 0=q 1=k 2=v
          int hh = (gcol >> 6) & 15;
          int d = gcol & 63;
          int bb = grow >> 11;
          int n = grow & 2047;
          if (which == 0) {
            qo[((size_t)(bb * NH + hh) * SEQ + n) * HD + d] = f2bf(val * QSCALE);
          } else if (which == 1) {
            ko[((size_t)(bb * NH + hh) * SEQ + n) * HD + d] = f2bf(val);
          } else {
            // V stored transposed: [B,H,hd,N]
            vo[((size_t)(bb * NH + hh) * HD + d) * SEQ + n] = f2bf(val);
          }
        } else {
          outf[(size_t)grow * DIM + gcol] = val;
        }
      }
}

// ---------------- flash attention with zoom bias (swapped-operand layout) ----------------
// grid: (SEQ/128) * B*H blocks; block 256 threads (4 waves, 32 q-rows each)
__global__ __launch_bounds__(256, 2) void attn_kernel(
    const unsigned short* __restrict__ qb, const unsigned short* __restrict__ kb,
    const unsigned short* __restrict__ vtb, const float* __restrict__ gamma,
    const float* __restrict__ dist, unsigned short* __restrict__ ab) {
  __shared__ __attribute__((aligned(16))) unsigned short Ks[64][PST];
  __shared__ __attribute__((aligned(16))) unsigned short Vt[64][PST];
  __shared__ __attribute__((aligned(16))) unsigned short Ps[4][32][PST];
  int tid = threadIdx.x;
  int lane = tid & 63;
  int w = tid >> 6;
  int idx = blockIdx.x;
  int bh = idx & 31;          // consecutive blocks share q-tile -> dist L2 reuse
  int qt = idx >> 5;
  int b = bh >> 4, h = bh & 15;
  int qrow0 = qt * 128 + w * 32;
  float g2 = gamma[bh] * LOG2E;

  const size_t base = (size_t)bh * SEQ * HD;      // q,k: [bh][n][d]
  const size_t vtbase = (size_t)bh * HD * SEQ;    // vt:  [bh][d][n]

  // Q fragments (B-operand layout: q=lane&15, k-chunk=(lane>>4)*8)
  bf16x8 qf[2][2];
  #pragma unroll
  for (int qs = 0; qs < 2; ++qs)
    #pragma unroll
    for (int kc = 0; kc < 2; ++kc)
      qf[qs][kc] = *reinterpret_cast<const bf16x8*>(
          &qb[base + (size_t)(qrow0 + qs * 16 + (lane & 15)) * HD + kc * 32 + (lane >> 4) * 8]);

  // per-lane dist row pointers (row = global q row, fixed per lane)
  const float* drow0 = dist + (size_t)(qrow0 + (lane & 15)) * SEQ;
  const float* drow1 = dist + (size_t)(qrow0 + 16 + (lane & 15)) * SEQ;

  // O^T accumulators: o[qs][db] rows d=db*16+(lane>>4)*4+j, col q=lane&15
  f32x4 o[2][4];
  #pragma unroll
  for (int qs = 0; qs < 2; ++qs)
    #pragma unroll
    for (int db = 0; db < 4; ++db) o[qs][db] = zero4();
  float m_run[2] = {-INFINITY, -INFINITY};
  float l_run[2] = {0.f, 0.f};

  // staging: chunk c = tid + 256*i; row=c>>3, off=(c&7)*8 shorts
  int sr0 = tid >> 3, sc0 = (tid & 7) * 8;        // chunk 0: rows 0..31
  int sr1 = sr0 + 32;                              // chunk 1: rows 32..63
  uint4 kr0, kr1, vr0, vr1;

  // prologue: tile 0
  {
    kr0 = *reinterpret_cast<const uint4*>(&kb[base + (size_t)(sr0) * HD + sc0]);
    kr1 = *reinterpret_cast<const uint4*>(&kb[base + (size_t)(sr1) * HD + sc0]);
    vr0 = *reinterpret_cast<const uint4*>(&vtb[vtbase + (size_t)sr0 * SEQ + sc0]);
    vr1 = *reinterpret_cast<const uint4*>(&vtb[vtbase + (size_t)sr1 * SEQ + sc0]);
    *reinterpret_cast<uint4*>(&Ks[sr0][sc0]) = kr0;
    *reinterpret_cast<uint4*>(&Ks[sr1][sc0]) = kr1;
    *reinterpret_cast<uint4*>(&Vt[sr0][sc0]) = vr0;
    *reinterpret_cast<uint4*>(&Vt[sr1][sc0]) = vr1;
  }
  __syncthreads();

  for (int mt = 0; mt < SEQ / 64; ++mt) {
    int m0 = mt * 64;
    // early-issue global loads for next tile (T14)
    if (mt + 1 < SEQ / 64) {
      int m1 = m0 + 64;
      kr0 = *reinterpret_cast<const uint4*>(&kb[base + (size_t)(m1 + sr0) * HD + sc0]);
      kr1 = *reinterpret_cast<const uint4*>(&kb[base + (size_t)(m1 + sr1) * HD + sc0]);
      vr0 = *reinterpret_cast<const uint4*>(&vtb[vtbase + (size_t)sr0 * SEQ + m1 + sc0]);
      vr1 = *reinterpret_cast<const uint4*>(&vtb[vtbase + (size_t)sr1 * SEQ + m1 + sc0]);
    }
    // dist bias tiles (float4 per 16x16 block per q-sub-block)
    f32x4 dv[2][4];
    #pragma unroll
    for (int nb = 0; nb < 4; ++nb) {
      dv[0][nb] = *reinterpret_cast<const f32x4*>(drow0 + m0 + nb * 16 + (lane >> 4) * 4);
      dv[1][nb] = *reinterpret_cast<const f32x4*>(drow1 + m0 + nb * 16 + (lane >> 4) * 4);
    }

    // S^T = K Q^T : s[qs][nb] rows m, col q
    f32x4 s[2][4];
    #pragma unroll
    for (int qs = 0; qs < 2; ++qs)
      #pragma unroll
      for (int nb = 0; nb < 4; ++nb) s[qs][nb] = zero4();
    #pragma unroll
    for (int nb = 0; nb < 4; ++nb)
      #pragma unroll
      for (int kc = 0; kc < 2; ++kc) {
        bf16x8 kf = *reinterpret_cast<const bf16x8*>(
            &Ks[nb * 16 + (lane & 15)][kc * 32 + (lane >> 4) * 8]);
        #pragma unroll
        for (int qs = 0; qs < 2; ++qs)
          s[qs][nb] = __builtin_amdgcn_mfma_f32_16x16x32_bf16(kf, qf[qs][kc], s[qs][nb], 0, 0, 0);
      }

    // online softmax (all quantities lane-local; q = lane&15)
    #pragma unroll
    for (int qs = 0; qs < 2; ++qs) {
      float pm = -INFINITY;
      #pragma unroll
      for (int nb = 0; nb < 4; ++nb)
        #pragma unroll
        for (int j = 0; j < 4; ++j) {
          float v = __builtin_fmaf(-g2, dv[qs][nb][j], s[qs][nb][j]);
          s[qs][nb][j] = v;
          pm = fmaxf(pm, v);
        }
      pm = fmaxf(pm, __shfl_xor(pm, 16, 64));
      pm = fmaxf(pm, __shfl_xor(pm, 32, 64));
      float mn = fmaxf(m_run[qs], pm);
      float corr = exp2f(m_run[qs] - mn);
      m_run[qs] = mn;
      float psum = 0.f;
      #pragma unroll
      for (int nb = 0; nb < 4; ++nb) {
        float p0 = exp2f(s[qs][nb][0] - mn);
        float p1 = exp2f(s[qs][nb][1] - mn);
        float p2 = exp2f(s[qs][nb][2] - mn);
        float p3 = exp2f(s[qs][nb][3] - mn);
        psum += (p0 + p1) + (p2 + p3);
        ushort4 pw;
        pw.x = f2bf(p0); pw.y = f2bf(p1); pw.z = f2bf(p2); pw.w = f2bf(p3);
        *reinterpret_cast<ushort4*>(
            &Ps[w][qs * 16 + (lane & 15)][nb * 16 + (lane >> 4) * 4]) = pw;
      }
      psum += __shfl_xor(psum, 16, 64);
      psum += __shfl_xor(psum, 32, 64);
      l_run[qs] = l_run[qs] * corr + psum;
      #pragma unroll
      for (int db = 0; db < 4; ++db) {
        o[qs][db][0] *= corr; o[qs][db][1] *= corr;
        o[qs][db][2] *= corr; o[qs][db][3] *= corr;
      }
    }

    // O^T += V^T P^T : mfma(vtf, pf)
    #pragma unroll
    for (int kc = 0; kc < 2; ++kc) {
      bf16x8 pf[2];
      #pragma unroll
      for (int qs = 0; qs < 2; ++qs)
        pf[qs] = *reinterpret_cast<const bf16x8*>(
            &Ps[w][qs * 16 + (lane & 15)][kc * 32 + (lane >> 4) * 8]);
      #pragma unroll
      for (int db = 0; db < 4; ++db) {
        bf16x8 vtf = *reinterpret_cast<const bf16x8*>(
            &Vt[db * 16 + (lane & 15)][kc * 32 + (lane >> 4) * 8]);
        #pragma unroll
        for (int qs = 0; qs < 2; ++qs)
          o[qs][db] = __builtin_amdgcn_mfma_f32_16x16x32_bf16(vtf, pf[qs], o[qs][db], 0, 0, 0);
      }
    }

    __syncthreads();
    if (mt + 1 < SEQ / 64) {
      *reinterpret_cast<uint4*>(&Ks[sr0][sc0]) = kr0;
      *reinterpret_cast<uint4*>(&Ks[sr1][sc0]) = kr1;
      *reinterpret_cast<uint4*>(&Vt[sr0][sc0]) = vr0;
      *reinterpret_cast<uint4*>(&Vt[sr1][sc0]) = vr1;
    }
    __syncthreads();
  }

  // epilogue: O^T / l, write attn_out [B,N,H*hd] bf16 (8B packed along d)
  #pragma unroll
  for (int qs = 0; qs < 2; ++qs) {
    float rl = 1.0f / l_run[qs];
    size_t row = (size_t)b * SEQ + qrow0 + qs * 16 + (lane & 15);
    #pragma unroll
    for (int db = 0; db < 4; ++db) {
      ushort4 w4;
      w4.x = f2bf(o[qs][db][0] * rl);
      w4.y = f2bf(o[qs][db][1] * rl);
      w4.z = f2bf(o[qs][db][2] * rl);
      w4.w = f2bf(o[qs][db][3] * rl);
      *reinterpret_cast<ushort4*>(
          &ab[row * DIM + h * HD + db * 16 + (lane >> 4) * 4]) = w4;
    }
  }
}

extern "C" void kernel_launch(void* const* d_in, const int* in_sizes, int n_in,
                              void* d_out, int out_size, void* d_ws, size_t ws_size,
                              hipStream_t stream) {
  const float* x     = (const float*)d_in[0];
  const float* gamma = (const float*)d_in[1];
  const float* dist  = (const float*)d_in[2];
  const float* Wqkv  = (const float*)d_in[3];
  const float* bqkv  = (const float*)d_in[4];
  const float* Wproj = (const float*)d_in[5];
  const float* bproj = (const float*)d_in[6];
  float* out = (float*)d_out;

  char* ws = (char*)d_ws;
  unsigned short* xb     = (unsigned short*)(ws);                 // 8,388,608 B
  unsigned short* wqkvt  = (unsigned short*)(ws + 8388608);       // 6,291,456 B
  unsigned short* wprojt = (unsigned short*)(ws + 14680064);      // 2,097,152 B
  unsigned short* qbuf   = (unsigned short*)(ws + 16777216);      // [B,H,N,hd] (q pre-scaled)
  unsigned short* kbuf   = (unsigned short*)(ws + 25165824);      // [B,H,N,hd]
  unsigned short* vtbuf  = (unsigned short*)(ws + 33554432);      // [B,H,hd,N] (transposed)
  unsigned short* abuf   = (unsigned short*)(ws + 41943040);      // [B,N,DIM]

  convert_x<<<4096, 256, 0, stream>>>(x, xb, (BATCH * SEQ * DIM) / 4);
  transpose_convert<<<dim3(96, 32), dim3(32, 8), 0, stream>>>(Wqkv, wqkvt, DIM, 3 * DIM);
  transpose_convert<<<dim3(32, 32), dim3(32, 8), 0, stream>>>(Wproj, wprojt, DIM, DIM);
  // QKV: [4096,1024] x [1024,3072]
  gemm_bt<<<dim3(48, 64), 256, 0, stream>>>(xb, wqkvt, bqkv, DIM, 0, qbuf, kbuf, vtbuf, nullptr);
  // attention: 16 q-tiles x 32 bh
  attn_kernel<<<(SEQ / 128) * BATCH * NH, 256, 0, stream>>>(qbuf, kbuf, vtbuf, gamma, dist, abuf);
  // proj: [4096,1024] x [1024,1024]
  gemm_bt<<<dim3(16, 64), 256, 0, stream>>>(abuf, wprojt, bproj, DIM, 1, nullptr, nullptr, nullptr, out);
}

// Round 3
// 199.411 us; speedup vs baseline: 1.4474x; 1.1055x over previous
//
#include <hip/hip_runtime.h>
#include <cstdint>
#include <cstddef>

#define HD 64
#define NH 16
#define BATCH 2
#define SEQ 2048
#define DIM 1024
#define SCALE 0.03125f   // 1024^-0.5
#define LOG2E 1.4426950408889634f
#define QSCALE (SCALE * LOG2E)   // folded into q at QKV epilogue
#define PST 72                    // padded LDS stride for Ps (shorts)
#define NT (SEQ / 64)

typedef short bf16x8 __attribute__((ext_vector_type(8)));
typedef float f32x4 __attribute__((ext_vector_type(4)));

// global_load_lds, 16B per lane; LDS dest = wave-uniform base + lane*16
#define GL16(gp, lp) __builtin_amdgcn_global_load_lds( \
    (const __attribute__((address_space(1))) unsigned int*)(gp), \
    (__attribute__((address_space(3))) unsigned int*)(lp), 16, 0, 0)

static __device__ __forceinline__ unsigned short f2bf(float f) {
  union { float f; unsigned u; } a; a.f = f;
  unsigned r = a.u + 0x7fffu + ((a.u >> 16) & 1u);  // RNE
  return (unsigned short)(r >> 16);
}

static __device__ __forceinline__ f32x4 zero4() {
  f32x4 z; z[0] = 0.f; z[1] = 0.f; z[2] = 0.f; z[3] = 0.f; return z;
}

// ---------------- fp32 -> bf16 convert (vectorized) ----------------
__global__ void convert_x(const float* __restrict__ in, unsigned short* __restrict__ out, int n4) {
  int i = blockIdx.x * blockDim.x + threadIdx.x;
  if (i < n4) {
    float4 v = reinterpret_cast<const float4*>(in)[i];
    ushort4 o;
    o.x = f2bf(v.x); o.y = f2bf(v.y); o.z = f2bf(v.z); o.w = f2bf(v.w);
    reinterpret_cast<ushort4*>(out)[i] = o;
  }
}

// ---------------- transpose + convert: in[R][C] fp32 -> out[C][R] bf16 ----------------
__global__ void transpose_convert(const float* __restrict__ in, unsigned short* __restrict__ out,
                                  int R, int C) {
  __shared__ float tile[32][33];
  int bx = blockIdx.x * 32;
  int by = blockIdx.y * 32;
  int tx = threadIdx.x, ty = threadIdx.y;  // block (32,8)
  #pragma unroll
  for (int i = 0; i < 32; i += 8)
    tile[ty + i][tx] = in[(size_t)(by + ty + i) * C + bx + tx];
  __syncthreads();
  #pragma unroll
  for (int i = 0; i < 32; i += 8)
    out[(size_t)(bx + ty + i) * R + by + tx] = f2bf(tile[tx][ty + i]);
}

// ---------------- GEMM: C[m][n] = sum_k A[m][k] * Bt[n][k]  (A,Bt bf16; fp32 acc) -------
__global__ __launch_bounds__(256) void gemm_bt(
    const unsigned short* __restrict__ A, const unsigned short* __restrict__ Bt,
    const float* __restrict__ bias, int K, int mode,
    unsigned short* __restrict__ qo, unsigned short* __restrict__ ko,
    unsigned short* __restrict__ vo, float* __restrict__ outf) {
  __shared__ __attribute__((aligned(16))) unsigned short As[64][72];
  __shared__ __attribute__((aligned(16))) unsigned short Bs[64][72];
  int tid = threadIdx.x;
  int lane = tid & 63;
  int w = tid >> 6;
  int wm = w >> 1, wn = w & 1;
  int m0 = blockIdx.y * 64, n0 = blockIdx.x * 64;
  int r0 = tid >> 3, c0 = (tid & 7) * 8;

  f32x4 acc[2][2];
  #pragma unroll
  for (int mr = 0; mr < 2; ++mr)
    #pragma unroll
    for (int nr = 0; nr < 2; ++nr) acc[mr][nr] = zero4();

  int nkt = K / 64;
  for (int kt = 0; kt < nkt; ++kt) {
    int k0 = kt * 64;
    uint4 a0 = *reinterpret_cast<const uint4*>(&A[(size_t)(m0 + r0) * K + k0 + c0]);
    uint4 a1 = *reinterpret_cast<const uint4*>(&A[(size_t)(m0 + r0 + 32) * K + k0 + c0]);
    uint4 b0 = *reinterpret_cast<const uint4*>(&Bt[(size_t)(n0 + r0) * K + k0 + c0]);
    uint4 b1 = *reinterpret_cast<const uint4*>(&Bt[(size_t)(n0 + r0 + 32) * K + k0 + c0]);
    *reinterpret_cast<uint4*>(&As[r0][c0]) = a0;
    *reinterpret_cast<uint4*>(&As[r0 + 32][c0]) = a1;
    *reinterpret_cast<uint4*>(&Bs[r0][c0]) = b0;
    *reinterpret_cast<uint4*>(&Bs[r0 + 32][c0]) = b1;
    __syncthreads();
    #pragma unroll
    for (int kc = 0; kc < 2; ++kc) {
      bf16x8 af[2], bfr[2];
      #pragma unroll
      for (int mr = 0; mr < 2; ++mr)
        af[mr] = *reinterpret_cast<const bf16x8*>(
            &As[wm * 32 + mr * 16 + (lane & 15)][kc * 32 + (lane >> 4) * 8]);
      #pragma unroll
      for (int nr = 0; nr < 2; ++nr)
        bfr[nr] = *reinterpret_cast<const bf16x8*>(
            &Bs[wn * 32 + nr * 16 + (lane & 15)][kc * 32 + (lane >> 4) * 8]);
      #pragma unroll
      for (int mr = 0; mr < 2; ++mr)
        #pragma unroll
        for (int nr = 0; nr < 2; ++nr)
          acc[mr][nr] = __builtin_amdgcn_mfma_f32_16x16x32_bf16(af[mr], bfr[nr], acc[mr][nr], 0, 0, 0);
    }
    __syncthreads();
  }

  #pragma unroll
  for (int mr = 0; mr < 2; ++mr)
    #pragma unroll
    for (int nr = 0; nr < 2; ++nr)
      #pragma unroll
      for (int j = 0; j < 4; ++j) {
        int grow = m0 + wm * 32 + mr * 16 + (lane >> 4) * 4 + j;
        int gcol = n0 + wn * 32 + nr * 16 + (lane & 15);
        float val = acc[mr][nr][j] + bias[gcol];
        if (mode == 0) {
          int which = gcol >> 10;         // 0=q 1=k 2=v
          int hh = (gcol >> 6) & 15;
          int d = gcol & 63;
          int bb = grow >> 11;
          int n = grow & 2047;
          if (which == 0) {
            qo[((size_t)(bb * NH + hh) * SEQ + n) * HD + d] = f2bf(val * QSCALE);
          } else if (which == 1) {
            ko[((size_t)(bb * NH + hh) * SEQ + n) * HD + d] = f2bf(val);
          } else {
            // V stored transposed: [B,H,hd,N]
            vo[((size_t)(bb * NH + hh) * HD + d) * SEQ + n] = f2bf(val);
          }
        } else {
          outf[(size_t)grow * DIM + gcol] = val;
        }
      }
}

// ---------------- flash attention with zoom bias (swapped-operand, dbuf LDS) ------------
// grid: (SEQ/128) * B*H blocks; block 256 threads (4 waves, 32 q-rows each)
__global__ __launch_bounds__(256, 2) void attn_kernel(
    const unsigned short* __restrict__ qb, const unsigned short* __restrict__ kb,
    const unsigned short* __restrict__ vtb, const float* __restrict__ gamma,
    const float* __restrict__ dist, unsigned short* __restrict__ ab) {
  // K/V tiles: XOR-swizzled layout, 128B rows, double-buffered.
  // LDS[r][slot s] (16B units) holds data of global 16B-chunk c = s ^ (r&7).
  __shared__ __attribute__((aligned(16))) unsigned short Ks[2][64][64];
  __shared__ __attribute__((aligned(16))) unsigned short Vt[2][64][64];
  __shared__ __attribute__((aligned(16))) unsigned short Ps[4][32][PST];
  const int tid = threadIdx.x;
  const int lane = tid & 63;
  const int w = tid >> 6;
  const int lo = lane & 15;
  const int hi = lane >> 4;
  const int idx = blockIdx.x;
  const int bh = idx & 31;          // consecutive blocks share q-tile -> dist L2 reuse
  const int qt = idx >> 5;
  const int b = bh >> 4, h = bh & 15;
  const int qrow0 = qt * 128 + w * 32;
  const float g2 = gamma[bh] * LOG2E;

  const size_t base = (size_t)bh * SEQ * HD;      // q,k: [bh][n][d]
  const size_t vtbase = (size_t)bh * HD * SEQ;    // vt:  [bh][d][n]

  // Q fragments (B-operand layout: q=lane&15, k-chunk=(lane>>4)*8)
  bf16x8 qf[2][2];
  #pragma unroll
  for (int qs = 0; qs < 2; ++qs)
    #pragma unroll
    for (int kc = 0; kc < 2; ++kc)
      qf[qs][kc] = *reinterpret_cast<const bf16x8*>(
          &qb[base + (size_t)(qrow0 + qs * 16 + lo) * HD + kc * 32 + hi * 8]);

  // per-lane dist row pointers (q-row fixed per lane; hi*4 folded in)
  const float* drow0 = dist + (size_t)(qrow0 + lo) * SEQ + hi * 4;
  const float* drow1 = drow0 + (size_t)16 * SEQ;

  // O^T accumulators: o[qs][db] rows d=db*16+hi*4+j, col q=lo
  f32x4 o[2][4];
  #pragma unroll
  for (int qs = 0; qs < 2; ++qs)
    #pragma unroll
    for (int db = 0; db < 4; ++db) o[qs][db] = zero4();
  float m_run[2] = {-INFINITY, -INFINITY};
  float l_run[2] = {0.f, 0.f};

  // staging: pre-swizzled global source, linear LDS dest (rule #21)
  const int srow = tid >> 3;                       // 0..31
  const int schunk = (tid & 7) ^ (srow & 7);       // 16B chunk in source row
  const unsigned short* ksrc0 = kb + base + (size_t)srow * HD + schunk * 8;
  const unsigned short* ksrc1 = ksrc0 + (size_t)32 * HD;
  const unsigned short* vsrc0 = vtb + vtbase + (size_t)srow * SEQ + schunk * 8;
  const unsigned short* vsrc1 = vsrc0 + (size_t)32 * SEQ;

  // prologue: stage tile 0 into buf 0; load dist tile 0
  GL16(ksrc0, &Ks[0][w * 8][0]);
  GL16(ksrc1, &Ks[0][32 + w * 8][0]);
  GL16(vsrc0, &Vt[0][w * 8][0]);
  GL16(vsrc1, &Vt[0][32 + w * 8][0]);
  f32x4 dvc[2][4], dvn[2][4];
  #pragma unroll
  for (int nb = 0; nb < 4; ++nb) {
    dvc[0][nb] = *reinterpret_cast<const f32x4*>(drow0 + nb * 16);
    dvc[1][nb] = *reinterpret_cast<const f32x4*>(drow1 + nb * 16);
  }
  __syncthreads();

  for (int mt = 0; mt < NT; ++mt) {
    const int cur = mt & 1;
    // stage tile mt+1 into other buffer; prefetch dist tile mt+1
    if (mt + 1 < NT) {
      const int m1 = (mt + 1) * 64;
      GL16(ksrc0 + (size_t)m1 * HD, &Ks[cur ^ 1][w * 8][0]);
      GL16(ksrc1 + (size_t)m1 * HD, &Ks[cur ^ 1][32 + w * 8][0]);
      GL16(vsrc0 + m1, &Vt[cur ^ 1][w * 8][0]);
      GL16(vsrc1 + m1, &Vt[cur ^ 1][32 + w * 8][0]);
      #pragma unroll
      for (int nb = 0; nb < 4; ++nb) {
        dvn[0][nb] = *reinterpret_cast<const f32x4*>(drow0 + m1 + nb * 16);
        dvn[1][nb] = *reinterpret_cast<const f32x4*>(drow1 + m1 + nb * 16);
      }
    }

    // S^T = K Q^T : s[qs][nb] rows m, col q  (swizzled kf reads)
    f32x4 s[2][4];
    #pragma unroll
    for (int qs = 0; qs < 2; ++qs)
      #pragma unroll
      for (int nb = 0; nb < 4; ++nb) s[qs][nb] = zero4();
    __builtin_amdgcn_s_setprio(1);
    #pragma unroll
    for (int nb = 0; nb < 4; ++nb)
      #pragma unroll
      for (int kc = 0; kc < 2; ++kc) {
        bf16x8 kf = *reinterpret_cast<const bf16x8*>(
            &Ks[cur][nb * 16 + lo][((kc * 4 + hi) ^ (lo & 7)) * 8]);
        #pragma unroll
        for (int qs = 0; qs < 2; ++qs)
          s[qs][nb] = __builtin_amdgcn_mfma_f32_16x16x32_bf16(kf, qf[qs][kc], s[qs][nb], 0, 0, 0);
      }
    __builtin_amdgcn_s_setprio(0);

    // online softmax (lane-local; q = lo), bias from prefetched dist regs
    #pragma unroll
    for (int qs = 0; qs < 2; ++qs) {
      float pm = -INFINITY;
      #pragma unroll
      for (int nb = 0; nb < 4; ++nb)
        #pragma unroll
        for (int j = 0; j < 4; ++j) {
          float v = __builtin_fmaf(-g2, dvc[qs][nb][j], s[qs][nb][j]);
          s[qs][nb][j] = v;
          pm = fmaxf(pm, v);
        }
      pm = fmaxf(pm, __shfl_xor(pm, 16, 64));
      pm = fmaxf(pm, __shfl_xor(pm, 32, 64));
      float mn = fmaxf(m_run[qs], pm);
      float corr = exp2f(m_run[qs] - mn);
      m_run[qs] = mn;
      float psum = 0.f;
      #pragma unroll
      for (int nb = 0; nb < 4; ++nb) {
        float p0 = exp2f(s[qs][nb][0] - mn);
        float p1 = exp2f(s[qs][nb][1] - mn);
        float p2 = exp2f(s[qs][nb][2] - mn);
        float p3 = exp2f(s[qs][nb][3] - mn);
        psum += (p0 + p1) + (p2 + p3);
        ushort4 pw;
        pw.x = f2bf(p0); pw.y = f2bf(p1); pw.z = f2bf(p2); pw.w = f2bf(p3);
        *reinterpret_cast<ushort4*>(&Ps[w][qs * 16 + lo][nb * 16 + hi * 4]) = pw;
      }
      psum += __shfl_xor(psum, 16, 64);
      psum += __shfl_xor(psum, 32, 64);
      l_run[qs] = l_run[qs] * corr + psum;
      #pragma unroll
      for (int db = 0; db < 4; ++db) {
        o[qs][db][0] *= corr; o[qs][db][1] *= corr;
        o[qs][db][2] *= corr; o[qs][db][3] *= corr;
      }
    }

    // O^T += V^T P^T : mfma(vtf, pf)  (swizzled vtf reads)
    __builtin_amdgcn_s_setprio(1);
    #pragma unroll
    for (int kc = 0; kc < 2; ++kc) {
      bf16x8 pf[2];
      #pragma unroll
      for (int qs = 0; qs < 2; ++qs)
        pf[qs] = *reinterpret_cast<const bf16x8*>(
            &Ps[w][qs * 16 + lo][kc * 32 + hi * 8]);
      #pragma unroll
      for (int db = 0; db < 4; ++db) {
        bf16x8 vtf = *reinterpret_cast<const bf16x8*>(
            &Vt[cur][db * 16 + lo][((kc * 4 + hi) ^ (lo & 7)) * 8]);
        #pragma unroll
        for (int qs = 0; qs < 2; ++qs)
          o[qs][db] = __builtin_amdgcn_mfma_f32_16x16x32_bf16(vtf, pf[qs], o[qs][db], 0, 0, 0);
      }
    }
    __builtin_amdgcn_s_setprio(0);

    if (mt + 1 < NT) {
      #pragma unroll
      for (int qs = 0; qs < 2; ++qs)
        #pragma unroll
        for (int nb = 0; nb < 4; ++nb) dvc[qs][nb] = dvn[qs][nb];
    }
    __syncthreads();   // next tile staged (vmcnt drained) + all waves done reading cur
  }

  // epilogue: O^T / l, write attn_out [B,N,H*hd] bf16 (8B packed along d)
  #pragma unroll
  for (int qs = 0; qs < 2; ++qs) {
    float rl = 1.0f / l_run[qs];
    size_t row = (size_t)b * SEQ + qrow0 + qs * 16 + lo;
    #pragma unroll
    for (int db = 0; db < 4; ++db) {
      ushort4 w4;
      w4.x = f2bf(o[qs][db][0] * rl);
      w4.y = f2bf(o[qs][db][1] * rl);
      w4.z = f2bf(o[qs][db][2] * rl);
      w4.w = f2bf(o[qs][db][3] * rl);
      *reinterpret_cast<ushort4*>(&ab[row * DIM + h * HD + db * 16 + hi * 4]) = w4;
    }
  }
}

extern "C" void kernel_launch(void* const* d_in, const int* in_sizes, int n_in,
                              void* d_out, int out_size, void* d_ws, size_t ws_size,
                              hipStream_t stream) {
  const float* x     = (const float*)d_in[0];
  const float* gamma = (const float*)d_in[1];
  const float* dist  = (const float*)d_in[2];
  const float* Wqkv  = (const float*)d_in[3];
  const float* bqkv  = (const float*)d_in[4];
  const float* Wproj = (const float*)d_in[5];
  const float* bproj = (const float*)d_in[6];
  float* out = (float*)d_out;

  char* ws = (char*)d_ws;
  unsigned short* xb     = (unsigned short*)(ws);                 // 8,388,608 B
  unsigned short* wqkvt  = (unsigned short*)(ws + 8388608);       // 6,291,456 B
  unsigned short* wprojt = (unsigned short*)(ws + 14680064);      // 2,097,152 B
  unsigned short* qbuf   = (unsigned short*)(ws + 16777216);      // [B,H,N,hd] (q pre-scaled)
  unsigned short* kbuf   = (unsigned short*)(ws + 25165824);      // [B,H,N,hd]
  unsigned short* vtbuf  = (unsigned short*)(ws + 33554432);      // [B,H,hd,N] (transposed)
  unsigned short* abuf   = (unsigned short*)(ws + 41943040);      // [B,N,DIM]

  convert_x<<<4096, 256, 0, stream>>>(x, xb, (BATCH * SEQ * DIM) / 4);
  transpose_convert<<<dim3(96, 32), dim3(32, 8), 0, stream>>>(Wqkv, wqkvt, DIM, 3 * DIM);
  transpose_convert<<<dim3(32, 32), dim3(32, 8), 0, stream>>>(Wproj, wprojt, DIM, DIM);
  // QKV: [4096,1024] x [1024,3072]
  gemm_bt<<<dim3(48, 64), 256, 0, stream>>>(xb, wqkvt, bqkv, DIM, 0, qbuf, kbuf, vtbuf, nullptr);
  // attention: 16 q-tiles x 32 bh
  attn_kernel<<<(SEQ / 128) * BATCH * NH, 256, 0, stream>>>(qbuf, kbuf, vtbuf, gamma, dist, abuf);
  // proj: [4096,1024] x [1024,1024]
  gemm_bt<<<dim3(16, 64), 256, 0, stream>>>(abuf, wprojt, bproj, DIM, 1, nullptr, nullptr, nullptr, out);
}

// Round 4
// 172.440 us; speedup vs baseline: 1.6738x; 1.1564x over previous
//
#include <hip/hip_runtime.h>
#include <cstdint>
#include <cstddef>

#define HD 64
#define NH 16
#define BATCH 2
#define SEQ 2048
#define DIM 1024
#define SCALE 0.03125f   // 1024^-0.5
#define LOG2E 1.4426950408889634f
#define QSCALE (SCALE * LOG2E)   // folded into q at QKV epilogue
#define NT (SEQ / 64)

typedef short bf16x8 __attribute__((ext_vector_type(8)));
typedef float f32x4 __attribute__((ext_vector_type(4)));
typedef unsigned u32x2 __attribute__((ext_vector_type(2)));
typedef unsigned u32x4 __attribute__((ext_vector_type(4)));

// global_load_lds, 16B per lane; LDS dest = wave-uniform base + lane*16
#define GL16(gp, lp) __builtin_amdgcn_global_load_lds( \
    (const __attribute__((address_space(1))) unsigned int*)(gp), \
    (__attribute__((address_space(3))) unsigned int*)(lp), 16, 0, 0)

static __device__ __forceinline__ unsigned short f2bf(float f) {
  union { float f; unsigned u; } a; a.f = f;
  unsigned r = a.u + 0x7fffu + ((a.u >> 16) & 1u);  // RNE
  return (unsigned short)(r >> 16);
}

static __device__ __forceinline__ f32x4 zero4() {
  f32x4 z; z[0] = 0.f; z[1] = 0.f; z[2] = 0.f; z[3] = 0.f; return z;
}

// ---------------- fp32 -> bf16 convert (vectorized) ----------------
__global__ void convert_x(const float* __restrict__ in, unsigned short* __restrict__ out, int n4) {
  int i = blockIdx.x * blockDim.x + threadIdx.x;
  if (i < n4) {
    float4 v = reinterpret_cast<const float4*>(in)[i];
    ushort4 o;
    o.x = f2bf(v.x); o.y = f2bf(v.y); o.z = f2bf(v.z); o.w = f2bf(v.w);
    reinterpret_cast<ushort4*>(out)[i] = o;
  }
}

// ---------------- transpose + convert: in[R][C] fp32 -> out[C][R] bf16 ----------------
__global__ void transpose_convert(const float* __restrict__ in, unsigned short* __restrict__ out,
                                  int R, int C) {
  __shared__ float tile[32][33];
  int bx = blockIdx.x * 32;
  int by = blockIdx.y * 32;
  int tx = threadIdx.x, ty = threadIdx.y;  // block (32,8)
  #pragma unroll
  for (int i = 0; i < 32; i += 8)
    tile[ty + i][tx] = in[(size_t)(by + ty + i) * C + bx + tx];
  __syncthreads();
  #pragma unroll
  for (int i = 0; i < 32; i += 8)
    out[(size_t)(bx + ty + i) * R + by + tx] = f2bf(tile[tx][ty + i]);
}

// ------- GEMM 128x128 tile (m97-style, global_load_lds): C = A * Bt^T --------
// mode 0: scatter epilogue into q (pre-scaled)/k [B,H,N,hd] and v TRANSPOSED [B,H,hd,N]
// mode 1: fp32 epilogue into outf [M][DIM] (+bias)
__global__ __launch_bounds__(256) void gemm128(
    const unsigned short* __restrict__ A, const unsigned short* __restrict__ Bt,
    const float* __restrict__ bias, int K, int mode,
    unsigned short* __restrict__ qo, unsigned short* __restrict__ ko,
    unsigned short* __restrict__ vo, float* __restrict__ outf) {
  __shared__ __attribute__((aligned(16))) unsigned short As[128 * 64];
  __shared__ __attribute__((aligned(16))) unsigned short Bs[128 * 64];
  const int tid = threadIdx.x;
  const int lane = tid & 63, w = tid >> 6;
  const int lo = lane & 15, hi = lane >> 4;
  const int wm = w >> 1, wn = w & 1;
  const int m0 = blockIdx.y * 128, n0 = blockIdx.x * 128;
  const int srow = tid >> 3, scol = (tid & 7) * 8;
  const unsigned short* abase = A + (size_t)(m0 + srow) * K + scol;
  const unsigned short* bbase = Bt + (size_t)(n0 + srow) * K + scol;

  f32x4 acc[4][4];
  #pragma unroll
  for (int mr = 0; mr < 4; ++mr)
    #pragma unroll
    for (int nr = 0; nr < 4; ++nr) acc[mr][nr] = zero4();

  const int nkt = K / 64;
  for (int kt = 0; kt < nkt; ++kt) {
    const unsigned short* ak = abase + kt * 64;
    const unsigned short* bk = bbase + kt * 64;
    #pragma unroll
    for (int i = 0; i < 4; ++i) {
      GL16(ak + (size_t)(32 * i) * K, &As[(w * 64 + 256 * i) * 8]);
      GL16(bk + (size_t)(32 * i) * K, &Bs[(w * 64 + 256 * i) * 8]);
    }
    __syncthreads();
    __builtin_amdgcn_s_setprio(1);
    #pragma unroll
    for (int kc = 0; kc < 2; ++kc) {
      bf16x8 af[4], bfr[4];
      #pragma unroll
      for (int mr = 0; mr < 4; ++mr)
        af[mr] = *reinterpret_cast<const bf16x8*>(
            &As[(wm * 64 + mr * 16 + lo) * 64 + kc * 32 + hi * 8]);
      #pragma unroll
      for (int nr = 0; nr < 4; ++nr)
        bfr[nr] = *reinterpret_cast<const bf16x8*>(
            &Bs[(wn * 64 + nr * 16 + lo) * 64 + kc * 32 + hi * 8]);
      #pragma unroll
      for (int mr = 0; mr < 4; ++mr)
        #pragma unroll
        for (int nr = 0; nr < 4; ++nr)
          acc[mr][nr] = __builtin_amdgcn_mfma_f32_16x16x32_bf16(af[mr], bfr[nr], acc[mr][nr], 0, 0, 0);
    }
    __builtin_amdgcn_s_setprio(0);
    __syncthreads();
  }

  #pragma unroll
  for (int nr = 0; nr < 4; ++nr) {
    const int gcol = n0 + wn * 64 + nr * 16 + lo;
    const float bv = bias[gcol];
    #pragma unroll
    for (int mr = 0; mr < 4; ++mr)
      #pragma unroll
      for (int j = 0; j < 4; ++j) {
        const int grow = m0 + wm * 64 + mr * 16 + hi * 4 + j;
        float val = acc[mr][nr][j] + bv;
        if (mode == 0) {
          int which = gcol >> 10;         // 0=q 1=k 2=v
          int hh = (gcol >> 6) & 15;
          int d = gcol & 63;
          int bb = grow >> 11;
          int n = grow & 2047;
          if (which == 0) {
            qo[((size_t)(bb * NH + hh) * SEQ + n) * HD + d] = f2bf(val * QSCALE);
          } else if (which == 1) {
            ko[((size_t)(bb * NH + hh) * SEQ + n) * HD + d] = f2bf(val);
          } else {
            vo[((size_t)(bb * NH + hh) * HD + d) * SEQ + n] = f2bf(val);  // [B,H,hd,N]
          }
        } else {
          outf[(size_t)grow * DIM + gcol] = val;
        }
      }
  }
}

// ---------------- flash attention with zoom bias (swapped-operand, dbuf LDS) ------------
// grid: (SEQ/64) * B*H = 1024 blocks; block 256 threads (4 waves, 16 q-rows each)
__global__ __launch_bounds__(256, 4) void attn_kernel(
    const unsigned short* __restrict__ qb, const unsigned short* __restrict__ kb,
    const unsigned short* __restrict__ vtb, const float* __restrict__ gamma,
    const float* __restrict__ dist, unsigned short* __restrict__ ab) {
  // K/V tiles: XOR-swizzled layout, 128B rows, double-buffered.
  // LDS[r][slot s] (16B units) holds data of global 16B-chunk c = s ^ (r&7).
  __shared__ __attribute__((aligned(16))) unsigned short Ks[2][64 * 64];
  __shared__ __attribute__((aligned(16))) unsigned short Vt[2][64 * 64];
  // Ps: per-wave 16(q) x 64(m) bf16, full-XOR swizzle: 8B-chunk c stored at slot c^lo.
  __shared__ __attribute__((aligned(16))) unsigned short Ps[4 * 16 * 64];
  const int tid = threadIdx.x;
  const int lane = tid & 63;
  const int w = tid >> 6;
  const int lo = lane & 15;
  const int hi = lane >> 4;
  const int idx = blockIdx.x;
  const int bh = idx & 31;          // consecutive blocks share q-tile -> dist L2 reuse
  const int qt = idx >> 5;
  const int b = bh >> 4, h = bh & 15;
  const int qrow0 = qt * 64 + w * 16;
  const float g2 = gamma[bh] * LOG2E;

  const size_t base = (size_t)bh * SEQ * HD;      // q,k: [bh][n][d]
  const size_t vtbase = (size_t)bh * HD * SEQ;    // vt:  [bh][d][n]

  // Q fragments (B-operand layout: q=lo, k-chunk=hi*8)
  bf16x8 qf[2];
  #pragma unroll
  for (int kc = 0; kc < 2; ++kc)
    qf[kc] = *reinterpret_cast<const bf16x8*>(
        &qb[base + (size_t)(qrow0 + lo) * HD + kc * 32 + hi * 8]);

  // per-lane dist row pointer (q-row fixed per lane; hi*4 folded in)
  const float* drow = dist + (size_t)(qrow0 + lo) * SEQ + hi * 4;

  // O^T accumulators: o[db] rows d=db*16+hi*4+j, col q=lo
  f32x4 o[4];
  #pragma unroll
  for (int db = 0; db < 4; ++db) o[db] = zero4();
  float m_run = -INFINITY;
  float l_run = 0.f;

  // staging: pre-swizzled global source, linear LDS dest (rule #21)
  const int srow = tid >> 3;                       // 0..31
  const int schunk = (tid & 7) ^ (srow & 7);       // 16B chunk in source row
  const unsigned short* ksrc0 = kb + base + (size_t)srow * HD + schunk * 8;
  const unsigned short* ksrc1 = ksrc0 + (size_t)32 * HD;
  const unsigned short* vsrc0 = vtb + vtbase + (size_t)srow * SEQ + schunk * 8;
  const unsigned short* vsrc1 = vsrc0 + (size_t)32 * SEQ;

  unsigned short* const psw = &Ps[w * 1024 + lo * 64];   // this lane's Ps row

  f32x4 dvA[4], dvB[4];

  // prologue: stage tile 0 into buf 0; load dist tile 0
  GL16(ksrc0, &Ks[0][w * 512]);
  GL16(ksrc1, &Ks[0][2048 + w * 512]);
  GL16(vsrc0, &Vt[0][w * 512]);
  GL16(vsrc1, &Vt[0][2048 + w * 512]);
  #pragma unroll
  for (int nb = 0; nb < 4; ++nb)
    dvA[nb] = *reinterpret_cast<const f32x4*>(drow + nb * 16);
  __syncthreads();

#define TILE_BODY(CUR, NXT, MT, DVC, DVN)                                              \
  {                                                                                    \
    if ((MT) + 1 < NT) {                                                               \
      const int m1_ = ((MT) + 1) * 64;                                                 \
      GL16(ksrc0 + (size_t)m1_ * HD, &Ks[NXT][w * 512]);                               \
      GL16(ksrc1 + (size_t)m1_ * HD, &Ks[NXT][2048 + w * 512]);                        \
      GL16(vsrc0 + m1_, &Vt[NXT][w * 512]);                                            \
      GL16(vsrc1 + m1_, &Vt[NXT][2048 + w * 512]);                                     \
      _Pragma("unroll")                                                                \
      for (int nb = 0; nb < 4; ++nb)                                                   \
        DVN[nb] = *reinterpret_cast<const f32x4*>(drow + m1_ + nb * 16);               \
    }                                                                                  \
    f32x4 s[4];                                                                        \
    _Pragma("unroll")                                                                  \
    for (int nb = 0; nb < 4; ++nb) s[nb] = zero4();                                    \
    __builtin_amdgcn_s_setprio(1);                                                     \
    _Pragma("unroll")                                                                  \
    for (int nb = 0; nb < 4; ++nb)                                                     \
      _Pragma("unroll")                                                                \
      for (int kc = 0; kc < 2; ++kc) {                                                 \
        bf16x8 kf = *reinterpret_cast<const bf16x8*>(                                  \
            &Ks[CUR][(nb * 16 + lo) * 64 + ((kc * 4 + hi) ^ (lo & 7)) * 8]);           \
        s[nb] = __builtin_amdgcn_mfma_f32_16x16x32_bf16(kf, qf[kc], s[nb], 0, 0, 0);   \
      }                                                                                \
    __builtin_amdgcn_s_setprio(0);                                                     \
    float pm = -INFINITY;                                                              \
    _Pragma("unroll")                                                                  \
    for (int nb = 0; nb < 4; ++nb)                                                     \
      _Pragma("unroll")                                                                \
      for (int j = 0; j < 4; ++j) {                                                    \
        float v_ = __builtin_fmaf(-g2, DVC[nb][j], s[nb][j]);                          \
        s[nb][j] = v_;                                                                 \
        pm = fmaxf(pm, v_);                                                            \
      }                                                                                \
    pm = fmaxf(pm, __shfl_xor(pm, 16, 64));                                            \
    pm = fmaxf(pm, __shfl_xor(pm, 32, 64));                                            \
    if (!__all(pm <= m_run + 8.0f)) {                                                  \
      float mn_ = fmaxf(m_run, pm);                                                    \
      float corr_ = exp2f(m_run - mn_);                                                \
      m_run = mn_;                                                                     \
      l_run *= corr_;                                                                  \
      _Pragma("unroll")                                                                \
      for (int db = 0; db < 4; ++db) {                                                 \
        o[db][0] *= corr_; o[db][1] *= corr_;                                          \
        o[db][2] *= corr_; o[db][3] *= corr_;                                          \
      }                                                                                \
    }                                                                                  \
    float psum = 0.f;                                                                  \
    _Pragma("unroll")                                                                  \
    for (int nb = 0; nb < 4; ++nb) {                                                   \
      float p0 = exp2f(s[nb][0] - m_run);                                              \
      float p1 = exp2f(s[nb][1] - m_run);                                              \
      float p2 = exp2f(s[nb][2] - m_run);                                              \
      float p3 = exp2f(s[nb][3] - m_run);                                              \
      psum += (p0 + p1) + (p2 + p3);                                                   \
      unsigned pk0, pk1;                                                               \
      asm("v_cvt_pk_bf16_f32 %0, %1, %2" : "=v"(pk0) : "v"(p0), "v"(p1));              \
      asm("v_cvt_pk_bf16_f32 %0, %1, %2" : "=v"(pk1) : "v"(p2), "v"(p3));              \
      u32x2 pw_; pw_[0] = pk0; pw_[1] = pk1;                                           \
      *reinterpret_cast<u32x2*>(&psw[(((nb << 2) + hi) ^ lo) * 4]) = pw_;              \
    }                                                                                  \
    psum += __shfl_xor(psum, 16, 64);                                                  \
    psum += __shfl_xor(psum, 32, 64);                                                  \
    l_run += psum;                                                                     \
    __builtin_amdgcn_s_setprio(1);                                                     \
    _Pragma("unroll")                                                                  \
    for (int kc = 0; kc < 2; ++kc) {                                                   \
      u32x2 ra = *reinterpret_cast<const u32x2*>(&psw[(((kc << 3) + hi * 2) ^ lo) * 4]); \
      u32x2 rb = *reinterpret_cast<const u32x2*>(&psw[(((kc << 3) + hi * 2 + 1) ^ lo) * 4]); \
      u32x4 t_; t_[0] = ra[0]; t_[1] = ra[1]; t_[2] = rb[0]; t_[3] = rb[1];            \
      bf16x8 pf = __builtin_bit_cast(bf16x8, t_);                                      \
      _Pragma("unroll")                                                                \
      for (int db = 0; db < 4; ++db) {                                                 \
        bf16x8 vtf = *reinterpret_cast<const bf16x8*>(                                 \
            &Vt[CUR][(db * 16 + lo) * 64 + ((kc * 4 + hi) ^ (lo & 7)) * 8]);           \
        o[db] = __builtin_amdgcn_mfma_f32_16x16x32_bf16(vtf, pf, o[db], 0, 0, 0);      \
      }                                                                                \
    }                                                                                  \
    __builtin_amdgcn_s_setprio(0);                                                     \
    __syncthreads();                                                                   \
  }

  for (int mt = 0; mt < NT; mt += 2) {
    TILE_BODY(0, 1, mt, dvA, dvB)
    TILE_BODY(1, 0, mt + 1, dvB, dvA)
  }
#undef TILE_BODY

  // epilogue: O^T / l, write attn_out [B,N,H*hd] bf16 (8B packed along d)
  {
    float rl = 1.0f / l_run;
    size_t row = (size_t)b * SEQ + qrow0 + lo;
    #pragma unroll
    for (int db = 0; db < 4; ++db) {
      ushort4 w4;
      w4.x = f2bf(o[db][0] * rl);
      w4.y = f2bf(o[db][1] * rl);
      w4.z = f2bf(o[db][2] * rl);
      w4.w = f2bf(o[db][3] * rl);
      *reinterpret_cast<ushort4*>(&ab[row * DIM + h * HD + db * 16 + hi * 4]) = w4;
    }
  }
}

extern "C" void kernel_launch(void* const* d_in, const int* in_sizes, int n_in,
                              void* d_out, int out_size, void* d_ws, size_t ws_size,
                              hipStream_t stream) {
  const float* x     = (const float*)d_in[0];
  const float* gamma = (const float*)d_in[1];
  const float* dist  = (const float*)d_in[2];
  const float* Wqkv  = (const float*)d_in[3];
  const float* bqkv  = (const float*)d_in[4];
  const float* Wproj = (const float*)d_in[5];
  const float* bproj = (const float*)d_in[6];
  float* out = (float*)d_out;

  char* ws = (char*)d_ws;
  unsigned short* xb     = (unsigned short*)(ws);                 // 8,388,608 B
  unsigned short* wqkvt  = (unsigned short*)(ws + 8388608);       // 6,291,456 B
  unsigned short* wprojt = (unsigned short*)(ws + 14680064);      // 2,097,152 B
  unsigned short* qbuf   = (unsigned short*)(ws + 16777216);      // [B,H,N,hd] (q pre-scaled)
  unsigned short* kbuf   = (unsigned short*)(ws + 25165824);      // [B,H,N,hd]
  unsigned short* vtbuf  = (unsigned short*)(ws + 33554432);      // [B,H,hd,N] (transposed)
  unsigned short* abuf   = (unsigned short*)(ws + 41943040);      // [B,N,DIM]

  convert_x<<<4096, 256, 0, stream>>>(x, xb, (BATCH * SEQ * DIM) / 4);
  transpose_convert<<<dim3(96, 32), dim3(32, 8), 0, stream>>>(Wqkv, wqkvt, DIM, 3 * DIM);
  transpose_convert<<<dim3(32, 32), dim3(32, 8), 0, stream>>>(Wproj, wprojt, DIM, DIM);
  // QKV: [4096,1024] x [1024,3072]
  gemm128<<<dim3(24, 32), 256, 0, stream>>>(xb, wqkvt, bqkv, DIM, 0, qbuf, kbuf, vtbuf, nullptr);
  // attention: 32 q-tiles x 32 bh
  attn_kernel<<<(SEQ / 64) * BATCH * NH, 256, 0, stream>>>(qbuf, kbuf, vtbuf, gamma, dist, abuf);
  // proj: [4096,1024] x [1024,1024]
  gemm128<<<dim3(8, 32), 256, 0, stream>>>(abuf, wprojt, bproj, DIM, 1, nullptr, nullptr, nullptr, out);
}